// Round 3
// baseline (387.279 us; speedup 1.0000x reference)
//
#include <hip/hip_runtime.h>

typedef __attribute__((ext_vector_type(8))) short s16x8;
typedef __attribute__((ext_vector_type(4))) float f32x4;

static __device__ __forceinline__ short f2bf(float f) {
    unsigned u = __builtin_bit_cast(unsigned, f);
    u = (u + 0x7FFFu + ((u >> 16) & 1u)) >> 16;
    return (short)u;
}

__device__ __forceinline__ void gload16(const short* g, short* l) {
    __builtin_amdgcn_global_load_lds(
        (const __attribute__((address_space(1))) void*)g,
        (__attribute__((address_space(3))) void*)l,
        16, 0, 0);
}

// ---------------- transpose + fp32->bf16 convert:  W[K][N] f32 -> Wt[N][K] bf16
__global__ __launch_bounds__(256) void transpose_convert(
    const float* __restrict__ W, short* __restrict__ Wt, int K, int N)
{
    __shared__ float tile[32][33];
    const int bx = blockIdx.x * 32;  // N
    const int by = blockIdx.y * 32;  // K
    const int tx = threadIdx.x;      // 0..31
    const int ty = threadIdx.y;      // 0..7
    for (int i = 0; i < 32; i += 8)
        tile[ty + i][tx] = W[(size_t)(by + ty + i) * N + bx + tx];
    __syncthreads();
    for (int i = 0; i < 32; i += 8)
        Wt[(size_t)(bx + ty + i) * K + by + tx] = f2bf(tile[tx][ty + i]);
}

// ---------------- V transpose: qkv V-part [8][1024][12][64] -> vT[96][64][1024] bf16
__global__ __launch_bounds__(256) void transpose_v(
    const short* __restrict__ qkv, short* __restrict__ vT)
{
    __shared__ short tile[32][68];
    const int nt = blockIdx.x;   // 0..31
    const int bh = blockIdx.y;   // 0..95
    const int b = bh / 12, h = bh % 12;
    const int t = threadIdx.x;
    {
        const int ty = t >> 3, tx = t & 7;
        *(s16x8*)&tile[ty][tx * 8] =
            *(const s16x8*)(qkv + ((size_t)(b * 1024 + nt * 32 + ty)) * 2304 + 1536 + h * 64 + tx * 8);
    }
    __syncthreads();
    {
        const int d = t >> 2, tx = t & 3;
        s16x8 v;
#pragma unroll
        for (int i = 0; i < 8; i++) v[i] = tile[tx * 8 + i][d];
        *(s16x8*)(vT + ((size_t)(bh * 64 + d)) * 1024 + nt * 32 + tx * 8) = v;
    }
}

// ---------------- LayerNorm: x[8192][768] f32 -> out bf16
__global__ __launch_bounds__(256) void layernorm_kernel(
    const float* __restrict__ x, const float* __restrict__ g,
    const float* __restrict__ b, short* __restrict__ out)
{
    const int row = blockIdx.x;
    const float* xr = x + (size_t)row * 768;
    const int t = threadIdx.x;
    float v0 = xr[t], v1 = xr[t + 256], v2 = xr[t + 512];
    __shared__ float red[4];

    float s = v0 + v1 + v2;
    for (int off = 32; off >= 1; off >>= 1) s += __shfl_down(s, off, 64);
    if ((t & 63) == 0) red[t >> 6] = s;
    __syncthreads();
    const float mean = (red[0] + red[1] + red[2] + red[3]) * (1.0f / 768.0f);
    const float d0 = v0 - mean, d1 = v1 - mean, d2 = v2 - mean;
    __syncthreads();
    float ss = d0 * d0 + d1 * d1 + d2 * d2;
    for (int off = 32; off >= 1; off >>= 1) ss += __shfl_down(ss, off, 64);
    if ((t & 63) == 0) red[t >> 6] = ss;
    __syncthreads();
    const float var = (red[0] + red[1] + red[2] + red[3]) * (1.0f / 768.0f);
    const float rstd = rsqrtf(var + 1e-5f);
    out[(size_t)row * 768 + t]       = f2bf(d0 * rstd * g[t] + b[t]);
    out[(size_t)row * 768 + t + 256] = f2bf(d1 * rstd * g[t + 256] + b[t + 256]);
    out[(size_t)row * 768 + t + 512] = f2bf(d2 * rstd * g[t + 512] + b[t + 512]);
}

// ---------------- GEMM (m97 structure): C[M][N] = A[M][K](bf16) * Bt[N][K]^T + bias
template <int MODE>
__global__ __launch_bounds__(256) void gemm_bt(
    const short* __restrict__ A, const short* __restrict__ Bt,
    const float* __restrict__ bias, const float* __restrict__ res,
    void* __restrict__ out, int M, int N, int K)
{
    __shared__ __align__(16) short As[128 * 32];
    __shared__ __align__(16) short Bs[128 * 32];

    const int t = threadIdx.x;
    const int l = t & 63;
    const int w = t >> 6;
    const int wr = (w >> 1) * 64;
    const int wc = (w & 1) * 64;
    const int tm = blockIdx.y * 128;
    const int tn = blockIdx.x * 128;

    const int lrow = l >> 2;
    const int lcol = (l & 3) * 8;
    const int ca = w * 2;
    const short* aS0 = A  + (size_t)(tm + ca * 16 + lrow) * K + lcol;
    const short* aS1 = aS0 + (size_t)16 * K;
    const short* bS0 = Bt + (size_t)(tn + ca * 16 + lrow) * K + lcol;
    const short* bS1 = bS0 + (size_t)16 * K;
    short* lA0 = &As[ca * 512];
    short* lA1 = &As[ca * 512 + 512];
    short* lB0 = &Bs[ca * 512];
    short* lB1 = &Bs[ca * 512 + 512];

    const int fr = l & 15;
    const int kq = (l >> 4) * 8;

    f32x4 acc[4][4] = {};

    for (int k0 = 0; k0 < K; k0 += 32) {
        gload16(aS0 + k0, lA0);
        gload16(aS1 + k0, lA1);
        gload16(bS0 + k0, lB0);
        gload16(bS1 + k0, lB1);
        __syncthreads();

        s16x8 af[4], bfr[4];
#pragma unroll
        for (int m = 0; m < 4; m++) af[m]  = *(const s16x8*)&As[(wr + m * 16 + fr) * 32 + kq];
#pragma unroll
        for (int n = 0; n < 4; n++) bfr[n] = *(const s16x8*)&Bs[(wc + n * 16 + fr) * 32 + kq];
#pragma unroll
        for (int m = 0; m < 4; m++)
#pragma unroll
            for (int n = 0; n < 4; n++)
                acc[m][n] = __builtin_amdgcn_mfma_f32_16x16x32_bf16(af[m], bfr[n], acc[m][n], 0, 0, 0);
        __syncthreads();
    }

    const int fq = (l >> 4) * 4;
#pragma unroll
    for (int m = 0; m < 4; m++) {
#pragma unroll
        for (int n = 0; n < 4; n++) {
            const int col = tn + wc + n * 16 + fr;
            const float bv = bias[col];
#pragma unroll
            for (int j = 0; j < 4; j++) {
                const int row = tm + wr + m * 16 + fq + j;
                float v = acc[m][n][j] + bv;
                if (MODE == 2) v = 0.5f * v * (1.0f + erff(v * 0.70710678118f));
                if (MODE == 1) {
                    ((float*)out)[(size_t)row * N + col] = v + res[(size_t)row * N + col];
                } else {
                    ((short*)out)[(size_t)row * N + col] = f2bf(v);
                }
            }
        }
    }
}

// ---------------- Flash attention v2: no K/V LDS staging, no barriers in loop.
// grid: (8 q-tiles of 128, 96 b*h), block 256 (4 waves, each owns 32 q-rows)
__global__ __launch_bounds__(256) void attn_kernel(
    const short* __restrict__ qkv, const short* __restrict__ vTg,
    short* __restrict__ out)
{
    const int qt = blockIdx.x;  // 0..7
    const int bh = blockIdx.y;  // 0..95
    const int b = bh / 12, h = bh % 12;

    __shared__ __align__(16) short Ps[4][32][72];

    const int t = threadIdx.x;
    const int l = t & 63;
    const int w = t >> 6;
    const int fr = l & 15;
    const int kq = (l >> 4) * 8;
    const int fq = (l >> 4) * 4;
    const float kSc = 0.18033688011112042f;  // 0.125 * log2(e)

    const int q0 = b * 1024 + qt * 128 + w * 32;

    // Q fragments direct from global (row-major, contiguous k)
    s16x8 qa[2][2];
#pragma unroll
    for (int r = 0; r < 2; r++) {
        const short* qp = qkv + ((size_t)(q0 + r * 16 + fr)) * 2304 + h * 64;
        qa[r][0] = *(const s16x8*)(qp + kq);
        qa[r][1] = *(const s16x8*)(qp + 32 + kq);
    }

    const short* kbp = qkv + ((size_t)(b * 1024 + fr)) * 2304 + 768 + h * 64 + kq;
    const short* vbp = vTg + ((size_t)(bh * 64 + fr)) * 1024 + kq;

    f32x4 acc[2][4] = {};
    float m_run[2][4], l_part[2][4];
#pragma unroll
    for (int r = 0; r < 2; r++)
#pragma unroll
        for (int j = 0; j < 4; j++) { m_run[r][j] = -1e30f; l_part[r][j] = 0.f; }

    for (int kt = 0; kt < 16; kt++) {
        // K fragments direct from global (shared across both row-blocks)
        s16x8 kb[4][2];
#pragma unroll
        for (int n = 0; n < 4; n++) {
            const short* kp = kbp + (size_t)(kt * 64 + n * 16) * 2304;
            kb[n][0] = *(const s16x8*)kp;
            kb[n][1] = *(const s16x8*)(kp + 32);
        }

#pragma unroll
        for (int r = 0; r < 2; r++) {
            f32x4 s[4];
#pragma unroll
            for (int n = 0; n < 4; n++) {
                f32x4 sv = {};
                sv = __builtin_amdgcn_mfma_f32_16x16x32_bf16(qa[r][0], kb[n][0], sv, 0, 0, 0);
                sv = __builtin_amdgcn_mfma_f32_16x16x32_bf16(qa[r][1], kb[n][1], sv, 0, 0, 0);
                s[n] = sv;
            }
#pragma unroll
            for (int j = 0; j < 4; j++) {
                float s0 = s[0][j] * kSc, s1 = s[1][j] * kSc,
                      s2 = s[2][j] * kSc, s3 = s[3][j] * kSc;
                float mx = fmaxf(fmaxf(s0, s1), fmaxf(s2, s3));
                for (int off = 1; off < 16; off <<= 1)
                    mx = fmaxf(mx, __shfl_xor(mx, off, 64));
                const float mnew = fmaxf(m_run[r][j], mx);
                const float alpha = exp2f(m_run[r][j] - mnew);
                m_run[r][j] = mnew;
                const float p0 = exp2f(s0 - mnew), p1 = exp2f(s1 - mnew);
                const float p2 = exp2f(s2 - mnew), p3 = exp2f(s3 - mnew);
                l_part[r][j] = l_part[r][j] * alpha + (p0 + p1 + p2 + p3);
#pragma unroll
                for (int n = 0; n < 4; n++) acc[r][n][j] *= alpha;
                Ps[w][r * 16 + fq + j][fr]      = f2bf(p0);
                Ps[w][r * 16 + fq + j][16 + fr] = f2bf(p1);
                Ps[w][r * 16 + fq + j][32 + fr] = f2bf(p2);
                Ps[w][r * 16 + fq + j][48 + fr] = f2bf(p3);
            }
        }

        // V fragments direct from vT (row-major in d, contiguous keys)
        s16x8 vb[4][2];
#pragma unroll
        for (int n = 0; n < 4; n++) {
            const short* vp = vbp + (size_t)(n * 16) * 1024 + kt * 64;
            vb[n][0] = *(const s16x8*)vp;
            vb[n][1] = *(const s16x8*)(vp + 32);
        }

        // O += P V   (Ps is wave-local: DS pipe is in-order per wave, no barrier)
#pragma unroll
        for (int r = 0; r < 2; r++) {
            s16x8 pa0 = *(const s16x8*)&Ps[w][r * 16 + fr][kq];
            s16x8 pa1 = *(const s16x8*)&Ps[w][r * 16 + fr][32 + kq];
#pragma unroll
            for (int n = 0; n < 4; n++) {
                acc[r][n] = __builtin_amdgcn_mfma_f32_16x16x32_bf16(pa0, vb[n][0], acc[r][n], 0, 0, 0);
                acc[r][n] = __builtin_amdgcn_mfma_f32_16x16x32_bf16(pa1, vb[n][1], acc[r][n], 0, 0, 0);
            }
        }
    }

    // epilogue: cross-lane l reduction (deferred), then write
#pragma unroll
    for (int r = 0; r < 2; r++)
#pragma unroll
        for (int j = 0; j < 4; j++) {
            float ls = l_part[r][j];
            for (int off = 1; off < 16; off <<= 1)
                ls += __shfl_xor(ls, off, 64);
            const float rinv = 1.0f / ls;
            const int row = q0 + r * 16 + fq + j;
#pragma unroll
            for (int n = 0; n < 4; n++)
                out[(size_t)row * 768 + h * 64 + n * 16 + fr] = f2bf(acc[r][n][j] * rinv);
        }
}

extern "C" void kernel_launch(void* const* d_in, const int* in_sizes, int n_in,
                              void* d_out, int out_size, void* d_ws, size_t ws_size,
                              hipStream_t stream) {
    const float* x      = (const float*)d_in[0];
    const float* n1g    = (const float*)d_in[1];
    const float* n1b    = (const float*)d_in[2];
    const float* qkv_w  = (const float*)d_in[3];
    const float* qkv_b  = (const float*)d_in[4];
    const float* proj_w = (const float*)d_in[5];
    const float* proj_b = (const float*)d_in[6];
    const float* n2g    = (const float*)d_in[7];
    const float* n2b    = (const float*)d_in[8];
    const float* fc1_w  = (const float*)d_in[9];
    const float* fc1_b  = (const float*)d_in[10];
    const float* fc2_w  = (const float*)d_in[11];
    const float* fc2_b  = (const float*)d_in[12];
    float* out = (float*)d_out;

    char* ws = (char*)d_ws;
    short* qkv_wT  = (short*)(ws + 0);           // [2304][768] bf16
    short* proj_wT = (short*)(ws + 3538944);     // [768][768]
    short* fc1_wT  = (short*)(ws + 4718592);     // [3072][768]
    short* fc2_wT  = (short*)(ws + 9437184);     // [768][3072]
    short* bufA    = (short*)(ws + 14155776);    // 8192x768 bf16 (ln1/attn_out/ln2)
    short* bufB    = (short*)(ws + 26738688);    // 8192x3072 bf16 (qkv / h1)
    short* vT      = (short*)(ws + 64487424);    // 96x64x1024 bf16 (fits in bufB tail)
    float* bufC    = (float*)(ws + 77070336);    // 8192x768 f32 (x1)

    const dim3 tb(32, 8);
    transpose_convert<<<dim3(2304 / 32, 768 / 32), tb, 0, stream>>>(qkv_w, qkv_wT, 768, 2304);
    transpose_convert<<<dim3(768 / 32, 768 / 32),  tb, 0, stream>>>(proj_w, proj_wT, 768, 768);
    transpose_convert<<<dim3(3072 / 32, 768 / 32), tb, 0, stream>>>(fc1_w, fc1_wT, 768, 3072);
    transpose_convert<<<dim3(768 / 32, 3072 / 32), tb, 0, stream>>>(fc2_w, fc2_wT, 3072, 768);

    layernorm_kernel<<<8192, 256, 0, stream>>>(x, n1g, n1b, bufA);

    gemm_bt<0><<<dim3(2304 / 128, 8192 / 128), 256, 0, stream>>>(
        bufA, qkv_wT, qkv_b, nullptr, bufB, 8192, 2304, 768);

    transpose_v<<<dim3(32, 96), 256, 0, stream>>>(bufB, vT);

    attn_kernel<<<dim3(8, 96), 256, 0, stream>>>(bufB, vT, bufA);

    gemm_bt<1><<<dim3(768 / 128, 8192 / 128), 256, 0, stream>>>(
        bufA, proj_wT, proj_b, x, bufC, 8192, 768, 768);

    layernorm_kernel<<<8192, 256, 0, stream>>>(bufC, n2g, n2b, bufA);

    gemm_bt<2><<<dim3(3072 / 128, 8192 / 128), 256, 0, stream>>>(
        bufA, fc1_wT, fc1_b, nullptr, bufB, 8192, 3072, 768);

    gemm_bt<1><<<dim3(768 / 128, 8192 / 128), 256, 0, stream>>>(
        bufB, fc2_wT, fc2_b, bufC, out, 8192, 768, 3072);
}